// Round 1
// baseline (1689.249 us; speedup 1.0000x reference)
//
#include <hip/hip_runtime.h>
#include <stdint.h>

#define TSTEPS 1024
#define BATCH  32
#define DIMK   1024
#define HEADS  8
#define NHEAD  64
#define NPROJ  2048          // 4 * H * N
#define MROWS  (TSTEPS*BATCH)

typedef _Float16 f16;
typedef _Float16 f16x4 __attribute__((ext_vector_type(4)));
typedef _Float16 f16x8 __attribute__((ext_vector_type(8)));
typedef float    f32x4 __attribute__((ext_vector_type(4)));
typedef unsigned int u32;

#define AS_GLOBAL __attribute__((address_space(1)))
#define AS_LDS    __attribute__((address_space(3)))

__device__ __forceinline__ void load_lds_16B(const void* g, void* l){
  __builtin_amdgcn_global_load_lds((const AS_GLOBAL u32*)g, (AS_LDS u32*)l, 16, 0, 0);
}

__device__ __forceinline__ float sigmoid_fast(float x){
  return __builtin_amdgcn_rcpf(1.0f + __expf(-x));
}
// tanh(x) = 1 - 2/(exp(2x)+1); exp->inf => 1, exp->0 => -1 (saturates correctly)
__device__ __forceinline__ float tanh_fast(float x){
  float e = __expf(2.0f*x);
  return fmaf(-2.0f, __builtin_amdgcn_rcpf(e + 1.0f), 1.0f);
}

// ---------------- cast f32 -> f16 (vectorized) ----------------
__global__ __launch_bounds__(256) void cast_kernel(const float4* __restrict__ src,
                                                   f16x4* __restrict__ dst, int n4){
  int i = blockIdx.x*blockDim.x + threadIdx.x;
  int stride = gridDim.x*blockDim.x;
  for (; i < n4; i += stride){
    float4 v = src[i];
    f16x4 o = { (f16)v.x, (f16)v.y, (f16)v.z, (f16)v.w };
    dst[i] = o;
  }
}

// ---------------- GEMM: Y[m][n] = sum_k X[m][k] * W[n][k]  (both row-major, K contig) ----
#define BM 128
#define BN 128
#define BK 32

__global__ __launch_bounds__(256) void gemm_xwT(const f16* __restrict__ A,  // MROWS x DIMK
                                                const f16* __restrict__ B,  // NPROJ x DIMK
                                                f16* __restrict__ C){       // MROWS x NPROJ
  __shared__ f16 sA[BM*BK];   // 8 KB, row-major [128][32]
  __shared__ f16 sB[BN*BK];   // 8 KB
  const int t = threadIdx.x;
  const int w = t >> 6;
  const int l = t & 63;
  const int bm = blockIdx.x;
  const int bn = blockIdx.y;
  const int wr = w >> 1, wc = w & 1;   // wave grid 2x2, each wave does 64x64

  f32x4 acc[4][4] = {};

  // staging: thread t loads 16B = 8 f16; tile row = t/4 (+64 for 2nd instr), col8 = (t&3)*8
  const int srow = t >> 2;
  const int scol = (t & 3) * 8;
  const f16* gA0 = A + (size_t)(bm*BM + srow)*DIMK + scol;
  const f16* gB0 = B + (size_t)(bn*BN + srow)*DIMK + scol;
  char* sAb = (char*)sA;
  char* sBb = (char*)sB;
  const int ldsw = w*1024;   // wave-uniform LDS base (HW adds lane*16)

  for (int kk = 0; kk < DIMK/BK; ++kk){
    const f16* pa = gA0 + kk*BK;
    const f16* pb = gB0 + kk*BK;
    load_lds_16B(pa,           sAb + ldsw);
    load_lds_16B(pa + 64*DIMK, sAb + ldsw + 4096);
    load_lds_16B(pb,           sBb + ldsw);
    load_lds_16B(pb + 64*DIMK, sBb + ldsw + 4096);
    __syncthreads();

    f16x8 af[4], bf[4];
    #pragma unroll
    for (int mi=0; mi<4; ++mi){
      int arow = wr*64 + mi*16 + (l & 15);
      af[mi] = *(const f16x8*)(sAb + arow*64 + (l>>4)*16);
    }
    #pragma unroll
    for (int ni=0; ni<4; ++ni){
      int brow = wc*64 + ni*16 + (l & 15);
      bf[ni] = *(const f16x8*)(sBb + brow*64 + (l>>4)*16);
    }
    #pragma unroll
    for (int mi=0; mi<4; ++mi)
      #pragma unroll
      for (int ni=0; ni<4; ++ni)
        acc[mi][ni] = __builtin_amdgcn_mfma_f32_16x16x32_f16(af[mi], bf[ni], acc[mi][ni], 0, 0, 0);
    __syncthreads();
  }

  // C/D layout: col = l&15, row = (l>>4)*4 + reg
  const int crow0 = bm*BM + wr*64 + (l>>4)*4;
  const int ccol0 = bn*BN + wc*64 + (l & 15);
  #pragma unroll
  for (int mi=0; mi<4; ++mi)
    #pragma unroll
    for (int ni=0; ni<4; ++ni)
      #pragma unroll
      for (int r=0; r<4; ++r)
        C[(size_t)(crow0 + mi*16 + r)*NPROJ + ccol0 + ni*16] = (f16)acc[mi][ni][r];
}

// ---------------- recurrent scan ----------------
// One workgroup (4 waves) per (b,h) pair. lane = state row, wave w owns cols [w*16, w*16+16).
__global__ __launch_bounds__(256) void scan_kernel(const f16* __restrict__ Y,
                                                   const float* __restrict__ b_beta,
                                                   float* __restrict__ out,
                                                   float* __restrict__ S_out){
  const int p = blockIdx.x;          // 0..255
  const int b = p >> 3, h = p & 7;
  const int t = threadIdx.x;
  const int w = t >> 6, l = t & 63;

  __shared__ float red[2][4][64];

  float S[16];
  #pragma unroll
  for (int c=0;c<16;++c) S[c] = 0.f;

  const float bb = b_beta[h*NHEAD + l];
  const f16* p0 = Y + (size_t)b*NPROJ + h*NHEAD + l;
  const size_t ts = (size_t)BATCH*NPROJ;
  float* outp = out + (size_t)b*512 + h*NHEAD + l;

  // prefetch t=0
  float kR = (float)p0[0], vR = (float)p0[512], qR = (float)p0[1024], bR = (float)p0[1536];

  #pragma unroll 1
  for (int tt=0; tt<TSTEPS; ++tt){
    float kcur=kR, vcur=vR, qcur=qR, bcur=bR;
    if (tt < TSTEPS-1){
      const f16* pn = p0 + (size_t)(tt+1)*ts;
      kR=(float)pn[0]; vR=(float)pn[512]; qR=(float)pn[1024]; bR=(float)pn[1536];
    }

    // normalize k across the 64 lanes (each wave redundantly)
    float ss = kcur*kcur;
    #pragma unroll
    for (int d=1; d<64; d<<=1) ss += __shfl_xor(ss, d);
    float kn = kcur * __builtin_amdgcn_rcpf(__builtin_sqrtf(ss) + 1e-6f);
    float beta = sigmoid_fast(bcur + bb);

    // loop1: partial retrieved_r over this wave's 16 columns
    const int cb = w*16;
    float pa0 = 0.f, pa1 = 0.f;
    #pragma unroll
    for (int c=0;c<16;c+=2){
      pa0 = fmaf(S[c],   __shfl(kn, cb + c),     pa0);
      pa1 = fmaf(S[c+1], __shfl(kn, cb + c + 1), pa1);
    }
    red[0][w][l] = pa0 + pa1;
    __syncthreads();
    float retrieved = red[0][0][l] + red[0][1][l] + red[0][2][l] + red[0][3][l];
    float delta = vcur - retrieved;

    // loop2: state update + Sq partial
    float sq0 = 0.f, sq1 = 0.f;
    #pragma unroll
    for (int c=0;c<16;c+=2){
      float kc0 = __shfl(kn,   cb + c);
      float qc0 = __shfl(qcur, cb + c);
      float kc1 = __shfl(kn,   cb + c + 1);
      float qc1 = __shfl(qcur, cb + c + 1);
      float s0 = tanh_fast(fmaf(beta, S[c],   delta*kc0));
      float s1 = tanh_fast(fmaf(beta, S[c+1], delta*kc1));
      S[c] = s0; S[c+1] = s1;
      sq0 = fmaf(s0, qc0, sq0);
      sq1 = fmaf(s1, qc1, sq1);
    }
    red[1][w][l] = sq0 + sq1;
    __syncthreads();
    float Sq = red[1][0][l] + red[1][1][l] + red[1][2][l] + red[1][3][l];
    if (w == 0){
      float sg = sigmoid_fast(Sq);
      outp[(size_t)tt * (BATCH*512)] = Sq*Sq*sg;   // Sq * silu(Sq)
    }
  }

  // S_final: [B, H, n, n] -> offset ((b*H+h)*64 + row)*64 + col
  size_t sbase = ((size_t)p*NHEAD + l)*NHEAD + w*16;
  #pragma unroll
  for (int c=0;c<16;c+=4){
    float4 v4 = { S[c], S[c+1], S[c+2], S[c+3] };
    *(float4*)(S_out + sbase + c) = v4;
  }
}

// ---------------- launch ----------------
extern "C" void kernel_launch(void* const* d_in, const int* in_sizes, int n_in,
                              void* d_out, int out_size, void* d_ws, size_t ws_size,
                              hipStream_t stream){
  const float* x  = (const float*)d_in[0];
  const float* Wk = (const float*)d_in[1];
  const float* Wv = (const float*)d_in[2];
  const float* Wq = (const float*)d_in[3];
  const float* Wb = (const float*)d_in[4];
  const float* bb = (const float*)d_in[5];

  float* out = (float*)d_out;
  float* Sf  = out + (size_t)TSTEPS*BATCH*512;

  char* ws = (char*)d_ws;
  f16* xh = (f16*)ws;                               // 33554432 elts = 64 MB
  f16* wh = (f16*)(ws + 67108864);                  // 2097152 elts = 4 MB
  f16* Yh = (f16*)(ws + 67108864 + 4194304);        // 67108864 elts = 128 MB

  // casts (W order must match Y column blocks: k | v | q | beta)
  cast_kernel<<<2048, 256, 0, stream>>>((const float4*)x,  (f16x4*)xh, (MROWS*DIMK)/4);
  cast_kernel<<<512,  256, 0, stream>>>((const float4*)Wk, (f16x4*)(wh + 0*524288), 524288/4);
  cast_kernel<<<512,  256, 0, stream>>>((const float4*)Wv, (f16x4*)(wh + 1*524288), 524288/4);
  cast_kernel<<<512,  256, 0, stream>>>((const float4*)Wq, (f16x4*)(wh + 2*524288), 524288/4);
  cast_kernel<<<512,  256, 0, stream>>>((const float4*)Wb, (f16x4*)(wh + 3*524288), 524288/4);

  dim3 g(MROWS/BM, NPROJ/BN);
  gemm_xwT<<<g, 256, 0, stream>>>(xh, wh, Yh);

  scan_kernel<<<256, 256, 0, stream>>>(Yh, bb, out, Sf);
}

// Round 2
// 1431.389 us; speedup vs baseline: 1.1801x; 1.1801x over previous
//
#include <hip/hip_runtime.h>
#include <stdint.h>

#define TSTEPS 1024
#define BATCH  32
#define DIMK   1024
#define HEADS  8
#define NHEAD  64
#define NPROJ  2048          // 4 * H * N
#define MROWS  (TSTEPS*BATCH)

typedef _Float16 f16;
typedef _Float16 f16x4 __attribute__((ext_vector_type(4)));
typedef _Float16 f16x8 __attribute__((ext_vector_type(8)));
typedef float    f32x4 __attribute__((ext_vector_type(4)));
typedef unsigned int u32;

#define AS_GLOBAL __attribute__((address_space(1)))
#define AS_LDS    __attribute__((address_space(3)))

__device__ __forceinline__ void load_lds_16B(const void* g, void* l){
  __builtin_amdgcn_global_load_lds((const AS_GLOBAL u32*)g, (AS_LDS u32*)l, 16, 0, 0);
}

__device__ __forceinline__ float sigmoid_fast(float x){
  return __builtin_amdgcn_rcpf(1.0f + __expf(-x));
}
// tanh(x) = 1 - 2/(exp(2x)+1); exp->inf => 1, exp->0 => -1 (saturates correctly)
__device__ __forceinline__ float tanh_fast(float x){
  float e = __expf(2.0f*x);
  return fmaf(-2.0f, __builtin_amdgcn_rcpf(e + 1.0f), 1.0f);
}

// ---------------- cast f32 -> f16 (vectorized) ----------------
__global__ __launch_bounds__(256) void cast_kernel(const float4* __restrict__ src,
                                                   f16x4* __restrict__ dst, int n4){
  int i = blockIdx.x*blockDim.x + threadIdx.x;
  int stride = gridDim.x*blockDim.x;
  for (; i < n4; i += stride){
    float4 v = src[i];
    f16x4 o = { (f16)v.x, (f16)v.y, (f16)v.z, (f16)v.w };
    dst[i] = o;
  }
}

// ---------------- GEMM: Y[m][n] = sum_k X[m][k] * W[n][k] ----------------
#define BM 128
#define BN 128
#define BK 32

__global__ __launch_bounds__(256) void gemm_xwT(const f16* __restrict__ A,  // MROWS x DIMK
                                                const f16* __restrict__ B,  // NPROJ x DIMK
                                                f16* __restrict__ C){       // MROWS x NPROJ
  __shared__ f16 sA[BM*BK];
  __shared__ f16 sB[BN*BK];
  const int t = threadIdx.x;
  const int w = t >> 6;
  const int l = t & 63;
  const int bm = blockIdx.x;
  const int bn = blockIdx.y;
  const int wr = w >> 1, wc = w & 1;

  f32x4 acc[4][4] = {};

  const int srow = t >> 2;
  const int scol = (t & 3) * 8;
  const f16* gA0 = A + (size_t)(bm*BM + srow)*DIMK + scol;
  const f16* gB0 = B + (size_t)(bn*BN + srow)*DIMK + scol;
  char* sAb = (char*)sA;
  char* sBb = (char*)sB;
  const int ldsw = w*1024;

  for (int kk = 0; kk < DIMK/BK; ++kk){
    const f16* pa = gA0 + kk*BK;
    const f16* pb = gB0 + kk*BK;
    load_lds_16B(pa,           sAb + ldsw);
    load_lds_16B(pa + 64*DIMK, sAb + ldsw + 4096);
    load_lds_16B(pb,           sBb + ldsw);
    load_lds_16B(pb + 64*DIMK, sBb + ldsw + 4096);
    __syncthreads();

    f16x8 af[4], bf[4];
    #pragma unroll
    for (int mi=0; mi<4; ++mi){
      int arow = wr*64 + mi*16 + (l & 15);
      af[mi] = *(const f16x8*)(sAb + arow*64 + (l>>4)*16);
    }
    #pragma unroll
    for (int ni=0; ni<4; ++ni){
      int brow = wc*64 + ni*16 + (l & 15);
      bf[ni] = *(const f16x8*)(sBb + brow*64 + (l>>4)*16);
    }
    #pragma unroll
    for (int mi=0; mi<4; ++mi)
      #pragma unroll
      for (int ni=0; ni<4; ++ni)
        acc[mi][ni] = __builtin_amdgcn_mfma_f32_16x16x32_f16(af[mi], bf[ni], acc[mi][ni], 0, 0, 0);
    __syncthreads();
  }

  const int crow0 = bm*BM + wr*64 + (l>>4)*4;
  const int ccol0 = bn*BN + wc*64 + (l & 15);
  #pragma unroll
  for (int mi=0; mi<4; ++mi)
    #pragma unroll
    for (int ni=0; ni<4; ++ni)
      #pragma unroll
      for (int r=0; r<4; ++r)
        C[(size_t)(crow0 + mi*16 + r)*NPROJ + ccol0 + ni*16] = (f16)acc[mi][ni][r];
}

// ---------------- prep: in-place kn = k/(||k||+eps), bs = sigmoid(braw + bias) ----------
// one wave per (t*B+b, h) group; lane = element index
__global__ __launch_bounds__(256) void prep_kernel(f16* __restrict__ Y,
                                                   const float* __restrict__ b_beta){
  int g = blockIdx.x*4 + (threadIdx.x >> 6);   // [0, T*B*H)
  int l = threadIdx.x & 63;
  int h = g & 7;
  f16* y = Y + (size_t)(g >> 3)*NPROJ + h*NHEAD + l;
  float k  = (float)y[0];
  float br = (float)y[1536];
  float ss = k*k;
  #pragma unroll
  for (int d=1; d<64; d<<=1) ss += __shfl_xor(ss, d);
  y[0]    = (f16)(k * __builtin_amdgcn_rcpf(__builtin_sqrtf(ss) + 1e-6f));
  y[1536] = (f16)sigmoid_fast(br + b_beta[h*NHEAD + l]);
}

// ---------------- recurrent scan (1 barrier/step, fused reductions) ----------------
// One workgroup (4 waves) per (b,h). lane = state row, wave w owns cols [w*16, w*16+16).
// Per iter t: S(t)=tanh(beta*S+delta*k); partials for Sq(t) AND ret(t+1) reduced in ONE
// double-buffered LDS phase.
__global__ __launch_bounds__(256) void scan_kernel(const f16* __restrict__ Y,
                                                   float* __restrict__ out,
                                                   float* __restrict__ S_out){
  const int p = blockIdx.x;          // 0..255
  const int b = p >> 3, h = p & 7;
  const int t = threadIdx.x;
  const int w = t >> 6, l = t & 63;
  const int cb = w*16;

  __shared__ float red[2][2][4][64];   // [buf][sq/ret][wave][lane]

  float S[16];
  #pragma unroll
  for (int c=0;c<16;++c) S[c] = 0.f;

  const f16* p0 = Y + (size_t)b*NPROJ + h*NHEAD + l;
  const size_t ts = (size_t)BATCH*NPROJ;
  float* outp = out + (size_t)b*512 + h*NHEAD + l;

  // t=0 values (kn/bs already prepped in Y)
  float kn_c = (float)p0[0];
  float v0   = (float)p0[512];
  float q_c  = (float)p0[1024];
  float bet_c= (float)p0[1536];
  float delta_c = v0;                 // S=0 -> retrieved=0
  // t=1 values
  float kn_n=0.f, v_n=0.f, q_n=0.f, bs_n=0.f;
  {
    const f16* pn = p0 + ts;
    kn_n=(float)pn[0]; v_n=(float)pn[512]; q_n=(float)pn[1024]; bs_n=(float)pn[1536];
  }

  #pragma unroll 1
  for (int tt=0; tt<TSTEPS; ++tt){
    const int buf = tt & 1;
    // prefetch t+2
    float kp=0.f, vp=0.f, qp=0.f, bp=0.f;
    if (tt+2 < TSTEPS){
      const f16* pn = p0 + (size_t)(tt+2)*ts;
      kp=(float)pn[0]; vp=(float)pn[512]; qp=(float)pn[1024]; bp=(float)pn[1536];
    }

    float sq0=0.f, sq1=0.f, pr0=0.f, pr1=0.f;
    #pragma unroll
    for (int c=0;c<16;c+=2){
      float kc0 = __shfl(kn_c, cb+c),   kc1 = __shfl(kn_c, cb+c+1);
      float qc0 = __shfl(q_c,  cb+c),   qc1 = __shfl(q_c,  cb+c+1);
      float kx0 = __shfl(kn_n, cb+c),   kx1 = __shfl(kn_n, cb+c+1);
      float s0 = tanh_fast(fmaf(bet_c, S[c],   delta_c*kc0));
      float s1 = tanh_fast(fmaf(bet_c, S[c+1], delta_c*kc1));
      S[c]=s0; S[c+1]=s1;
      sq0 = fmaf(s0, qc0, sq0);  sq1 = fmaf(s1, qc1, sq1);
      pr0 = fmaf(s0, kx0, pr0);  pr1 = fmaf(s1, kx1, pr1);
    }
    red[buf][0][w][l] = sq0+sq1;
    red[buf][1][w][l] = pr0+pr1;
    __syncthreads();

    float Sq  = red[buf][0][0][l]+red[buf][0][1][l]+red[buf][0][2][l]+red[buf][0][3][l];
    if (w == (tt&3)){
      float sg = sigmoid_fast(Sq);
      outp[(size_t)tt * (BATCH*512)] = Sq*Sq*sg;   // Sq * silu(Sq)
    }
    float ret = red[buf][1][0][l]+red[buf][1][1][l]+red[buf][1][2][l]+red[buf][1][3][l];

    // rotate to t+1
    delta_c = v_n - ret;
    bet_c   = bs_n;
    kn_c    = kn_n;
    q_c     = q_n;
    kn_n=kp; v_n=vp; q_n=qp; bs_n=bp;
  }

  // S_final: [B, H, n, n]
  size_t sbase = ((size_t)p*NHEAD + l)*NHEAD + cb;
  #pragma unroll
  for (int c=0;c<16;c+=4){
    float4 v4 = { S[c], S[c+1], S[c+2], S[c+3] };
    *(float4*)(S_out + sbase + c) = v4;
  }
}

// ---------------- launch ----------------
extern "C" void kernel_launch(void* const* d_in, const int* in_sizes, int n_in,
                              void* d_out, int out_size, void* d_ws, size_t ws_size,
                              hipStream_t stream){
  const float* x  = (const float*)d_in[0];
  const float* Wk = (const float*)d_in[1];
  const float* Wv = (const float*)d_in[2];
  const float* Wq = (const float*)d_in[3];
  const float* Wb = (const float*)d_in[4];
  const float* bb = (const float*)d_in[5];

  float* out = (float*)d_out;
  float* Sf  = out + (size_t)TSTEPS*BATCH*512;

  char* ws = (char*)d_ws;
  f16* xh = (f16*)ws;                               // 64 MB
  f16* wh = (f16*)(ws + 67108864);                  // 4 MB
  f16* Yh = (f16*)(ws + 67108864 + 4194304);        // 128 MB

  cast_kernel<<<2048, 256, 0, stream>>>((const float4*)x,  (f16x4*)xh, (MROWS*DIMK)/4);
  cast_kernel<<<512,  256, 0, stream>>>((const float4*)Wk, (f16x4*)(wh + 0*524288), 524288/4);
  cast_kernel<<<512,  256, 0, stream>>>((const float4*)Wv, (f16x4*)(wh + 1*524288), 524288/4);
  cast_kernel<<<512,  256, 0, stream>>>((const float4*)Wq, (f16x4*)(wh + 2*524288), 524288/4);
  cast_kernel<<<512,  256, 0, stream>>>((const float4*)Wb, (f16x4*)(wh + 3*524288), 524288/4);

  dim3 g(MROWS/BM, NPROJ/BN);
  gemm_xwT<<<g, 256, 0, stream>>>(xh, wh, Yh);

  prep_kernel<<<(TSTEPS*BATCH*HEADS)/4, 256, 0, stream>>>(Yh, bb);

  scan_kernel<<<256, 256, 0, stream>>>(Yh, out, Sf);
}

// Round 3
// 1027.461 us; speedup vs baseline: 1.6441x; 1.3931x over previous
//
#include <hip/hip_runtime.h>
#include <stdint.h>

#define TSTEPS 1024
#define BATCH  32
#define DIMK   1024
#define HEADS  8
#define NHEAD  64
#define NPROJ  2048          // 4 * H * N
#define MROWS  (TSTEPS*BATCH)

typedef _Float16 f16;
typedef _Float16 f16x4 __attribute__((ext_vector_type(4)));
typedef _Float16 f16x8 __attribute__((ext_vector_type(8)));
typedef float    f32x4 __attribute__((ext_vector_type(4)));
typedef unsigned int u32;

#define AS_GLOBAL __attribute__((address_space(1)))
#define AS_LDS    __attribute__((address_space(3)))

__device__ __forceinline__ void load_lds_16B(const void* g, void* l){
  __builtin_amdgcn_global_load_lds((const AS_GLOBAL u32*)g, (AS_LDS u32*)l, 16, 0, 0);
}

__device__ __forceinline__ float sigmoid_fast(float x){
  return __builtin_amdgcn_rcpf(1.0f + __expf(-x));
}
// tanh(x) = 1 - 2/(exp(2x)+1); saturates correctly at +-1
__device__ __forceinline__ float tanh_fast(float x){
  float e = __expf(2.0f*x);
  return fmaf(-2.0f, __builtin_amdgcn_rcpf(e + 1.0f), 1.0f);
}

// ---------------- cast f32 -> f16 (vectorized) ----------------
__global__ __launch_bounds__(256) void cast_kernel(const float4* __restrict__ src,
                                                   f16x4* __restrict__ dst, int n4){
  int i = blockIdx.x*blockDim.x + threadIdx.x;
  int stride = gridDim.x*blockDim.x;
  for (; i < n4; i += stride){
    float4 v = src[i];
    f16x4 o = { (f16)v.x, (f16)v.y, (f16)v.z, (f16)v.w };
    dst[i] = o;
  }
}

// ---------------- GEMM: Y[m][n] = sum_k X[m][k] * W[n][k] ----------------
#define BM 128
#define BN 128
#define BK 32

__global__ __launch_bounds__(256) void gemm_xwT(const f16* __restrict__ A,  // MROWS x DIMK
                                                const f16* __restrict__ B,  // NPROJ x DIMK
                                                f16* __restrict__ C){       // MROWS x NPROJ
  __shared__ f16 sA[BM*BK];
  __shared__ f16 sB[BN*BK];
  const int t = threadIdx.x;
  const int w = t >> 6;
  const int l = t & 63;
  const int bm = blockIdx.x;
  const int bn = blockIdx.y;
  const int wr = w >> 1, wc = w & 1;

  f32x4 acc[4][4] = {};

  const int srow = t >> 2;
  const int scol = (t & 3) * 8;
  const f16* gA0 = A + (size_t)(bm*BM + srow)*DIMK + scol;
  const f16* gB0 = B + (size_t)(bn*BN + srow)*DIMK + scol;
  char* sAb = (char*)sA;
  char* sBb = (char*)sB;
  const int ldsw = w*1024;

  for (int kk = 0; kk < DIMK/BK; ++kk){
    const f16* pa = gA0 + kk*BK;
    const f16* pb = gB0 + kk*BK;
    load_lds_16B(pa,           sAb + ldsw);
    load_lds_16B(pa + 64*DIMK, sAb + ldsw + 4096);
    load_lds_16B(pb,           sBb + ldsw);
    load_lds_16B(pb + 64*DIMK, sBb + ldsw + 4096);
    __syncthreads();

    f16x8 af[4], bf[4];
    #pragma unroll
    for (int mi=0; mi<4; ++mi){
      int arow = wr*64 + mi*16 + (l & 15);
      af[mi] = *(const f16x8*)(sAb + arow*64 + (l>>4)*16);
    }
    #pragma unroll
    for (int ni=0; ni<4; ++ni){
      int brow = wc*64 + ni*16 + (l & 15);
      bf[ni] = *(const f16x8*)(sBb + brow*64 + (l>>4)*16);
    }
    #pragma unroll
    for (int mi=0; mi<4; ++mi)
      #pragma unroll
      for (int ni=0; ni<4; ++ni)
        acc[mi][ni] = __builtin_amdgcn_mfma_f32_16x16x32_f16(af[mi], bf[ni], acc[mi][ni], 0, 0, 0);
    __syncthreads();
  }

  const int crow0 = bm*BM + wr*64 + (l>>4)*4;
  const int ccol0 = bn*BN + wc*64 + (l & 15);
  #pragma unroll
  for (int mi=0; mi<4; ++mi)
    #pragma unroll
    for (int ni=0; ni<4; ++ni)
      #pragma unroll
      for (int r=0; r<4; ++r)
        C[(size_t)(crow0 + mi*16 + r)*NPROJ + ccol0 + ni*16] = (f16)acc[mi][ni][r];
}

// ---------------- prep: in-place kn = k/(||k||+eps), bs = sigmoid(braw + bias) ----------
__global__ __launch_bounds__(256) void prep_kernel(f16* __restrict__ Y,
                                                   const float* __restrict__ b_beta){
  int g = blockIdx.x*4 + (threadIdx.x >> 6);   // [0, T*B*H)
  int l = threadIdx.x & 63;
  int h = g & 7;
  f16* y = Y + (size_t)(g >> 3)*NPROJ + h*NHEAD + l;
  float k  = (float)y[0];
  float br = (float)y[1536];
  float ss = k*k;
  #pragma unroll
  for (int d=1; d<64; d<<=1) ss += __shfl_xor(ss, d);
  y[0]    = (f16)(k * __builtin_amdgcn_rcpf(__builtin_sqrtf(ss) + 1e-6f));
  y[1536] = (f16)sigmoid_fast(br + b_beta[h*NHEAD + l]);
}

// ---------------- recurrent scan: barrier-free, 512 threads/pair ----------------
// thread t: row = t>>3 (0..63), col group g = t&7 owns cols [g*8, g*8+8).
// All reductions are 3-stage shfl_xor within the row's 8 lanes. No LDS, no barriers.
__global__ __launch_bounds__(512) void scan_kernel(const f16* __restrict__ Y,
                                                   float* __restrict__ out,
                                                   float* __restrict__ S_out){
  const int p = blockIdx.x;          // pair 0..255
  const int b = p >> 3, h = p & 7;
  const int t = threadIdx.x;         // 0..511
  const int row = t >> 3;
  const int g   = t & 7;
  const int cb  = g*8;

  float S[8];
  #pragma unroll
  for (int c=0;c<8;++c) S[c] = 0.f;

  const f16* base = Y + (size_t)b*NPROJ + h*NHEAD;
  const size_t ts = (size_t)BATCH*NPROJ;
  float* outp = out + (size_t)b*512 + h*NHEAD + row;

  // prefetch stages A (t), B (t+1)
  f16x8 kA = *(const f16x8*)(base + cb);
  f16x8 qA = *(const f16x8*)(base + 1024 + cb);
  float vA = (float)base[512 + row];
  float bA = (float)base[1536 + row];
  f16x8 kB = *(const f16x8*)(base + ts + cb);
  f16x8 qB = *(const f16x8*)(base + ts + 1024 + cb);
  float vB = (float)base[ts + 512 + row];
  float bB = (float)base[ts + 1536 + row];

  #pragma unroll 1
  for (int tt=0; tt<TSTEPS; ++tt){
    // prefetch t+2 into C
    f16x8 kC = {}, qC = {};
    float vC = 0.f, bC = 0.f;
    if (tt+2 < TSTEPS){
      const f16* pn = base + (size_t)(tt+2)*ts;
      kC = *(const f16x8*)(pn + cb);
      qC = *(const f16x8*)(pn + 1024 + cb);
      vC = (float)pn[512 + row];
      bC = (float)pn[1536 + row];
    }

    float kf[8], qf[8];
    #pragma unroll
    for (int j=0;j<8;++j){ kf[j] = (float)kA[j]; qf[j] = (float)qA[j]; }

    // retrieved[row] partial over this lane's 8 cols, then 8-lane reduce
    float r0=0.f, r1=0.f;
    #pragma unroll
    for (int j=0;j<8;j+=2){ r0 = fmaf(S[j], kf[j], r0); r1 = fmaf(S[j+1], kf[j+1], r1); }
    float ret = r0 + r1;
    ret += __shfl_xor(ret, 1);
    ret += __shfl_xor(ret, 2);
    ret += __shfl_xor(ret, 4);
    float delta = vA - ret;

    // state update + Sq partial
    float s0=0.f, s1=0.f;
    #pragma unroll
    for (int j=0;j<8;j+=2){
      float a0 = tanh_fast(fmaf(bA, S[j],   delta*kf[j]));
      float a1 = tanh_fast(fmaf(bA, S[j+1], delta*kf[j+1]));
      S[j] = a0; S[j+1] = a1;
      s0 = fmaf(a0, qf[j],   s0);
      s1 = fmaf(a1, qf[j+1], s1);
    }
    float Sq = s0 + s1;
    Sq += __shfl_xor(Sq, 1);
    Sq += __shfl_xor(Sq, 2);
    Sq += __shfl_xor(Sq, 4);
    if (g == 0){
      float sg = sigmoid_fast(Sq);
      outp[(size_t)tt * (BATCH*512)] = Sq*Sq*sg;   // Sq * silu(Sq)
    }

    // rotate prefetch stages
    kA = kB; qA = qB; vA = vB; bA = bB;
    kB = kC; qB = qC; vB = vC; bB = bC;
  }

  // S_final: [B, H, n, n] -> ((p*64 + row)*64 + cb)
  size_t sbase = ((size_t)p*NHEAD + row)*NHEAD + cb;
  float4 lo = { S[0], S[1], S[2], S[3] };
  float4 hi = { S[4], S[5], S[6], S[7] };
  *(float4*)(S_out + sbase)     = lo;
  *(float4*)(S_out + sbase + 4) = hi;
}

// ---------------- launch ----------------
extern "C" void kernel_launch(void* const* d_in, const int* in_sizes, int n_in,
                              void* d_out, int out_size, void* d_ws, size_t ws_size,
                              hipStream_t stream){
  const float* x  = (const float*)d_in[0];
  const float* Wk = (const float*)d_in[1];
  const float* Wv = (const float*)d_in[2];
  const float* Wq = (const float*)d_in[3];
  const float* Wb = (const float*)d_in[4];
  const float* bb = (const float*)d_in[5];

  float* out = (float*)d_out;
  float* Sf  = out + (size_t)TSTEPS*BATCH*512;

  char* ws = (char*)d_ws;
  f16* xh = (f16*)ws;                               // 64 MB
  f16* wh = (f16*)(ws + 67108864);                  // 4 MB
  f16* Yh = (f16*)(ws + 67108864 + 4194304);        // 128 MB

  cast_kernel<<<2048, 256, 0, stream>>>((const float4*)x,  (f16x4*)xh, (MROWS*DIMK)/4);
  cast_kernel<<<512,  256, 0, stream>>>((const float4*)Wk, (f16x4*)(wh + 0*524288), 524288/4);
  cast_kernel<<<512,  256, 0, stream>>>((const float4*)Wv, (f16x4*)(wh + 1*524288), 524288/4);
  cast_kernel<<<512,  256, 0, stream>>>((const float4*)Wq, (f16x4*)(wh + 2*524288), 524288/4);
  cast_kernel<<<512,  256, 0, stream>>>((const float4*)Wb, (f16x4*)(wh + 3*524288), 524288/4);

  dim3 g(MROWS/BM, NPROJ/BN);
  gemm_xwT<<<g, 256, 0, stream>>>(xh, wh, Yh);

  prep_kernel<<<(TSTEPS*BATCH*HEADS)/4, 256, 0, stream>>>(Yh, bb);

  scan_kernel<<<256, 512, 0, stream>>>(Yh, out, Sf);
}

// Round 5
// 1000.332 us; speedup vs baseline: 1.6887x; 1.0271x over previous
//
#include <hip/hip_runtime.h>
#include <stdint.h>

#define TSTEPS 1024
#define BATCH  32
#define DIMK   1024
#define HEADS  8
#define NHEAD  64
#define NPROJ  2048          // 4 * H * N
#define MROWS  (TSTEPS*BATCH)

typedef _Float16 f16;
typedef _Float16 f16x2 __attribute__((ext_vector_type(2)));
typedef _Float16 f16x4 __attribute__((ext_vector_type(4)));
typedef _Float16 f16x8 __attribute__((ext_vector_type(8)));
typedef float    f32x4 __attribute__((ext_vector_type(4)));
typedef unsigned int u32;

#define AS_GLOBAL __attribute__((address_space(1)))
#define AS_LDS    __attribute__((address_space(3)))

__device__ __forceinline__ void load_lds_16B(const void* g, void* l){
  __builtin_amdgcn_global_load_lds((const AS_GLOBAL u32*)g, (AS_LDS u32*)l, 16, 0, 0);
}

#define LOG2E 1.4426950408889634f

__device__ __forceinline__ float sigmoid_fast(float x){
  return __builtin_amdgcn_rcpf(1.0f + exp2f(-x * LOG2E));
}
// tanh(x) = 1 - 2/(exp(2x)+1); saturates correctly at +-1
__device__ __forceinline__ float tanh_fast(float x){
  float e = exp2f(x * (2.0f*LOG2E));
  return fmaf(-2.0f, __builtin_amdgcn_rcpf(e + 1.0f), 1.0f);
}

__device__ __forceinline__ float fdot2(f16x2 a, f16x2 b, float c){
#if __has_builtin(__builtin_amdgcn_fdot2)
  typedef __fp16 h16x2 __attribute__((ext_vector_type(2)));
  return __builtin_amdgcn_fdot2(__builtin_bit_cast(h16x2, a),
                                __builtin_bit_cast(h16x2, b), c, false);
#else
  return fmaf((float)a[1], (float)b[1], fmaf((float)a[0], (float)b[0], c));
#endif
}

__device__ __forceinline__ f16x2 pack2(float a, float b){
#if __has_builtin(__builtin_amdgcn_cvt_pkrtz)
  return __builtin_bit_cast(f16x2, __builtin_amdgcn_cvt_pkrtz(a, b));
#else
  f16x2 r = { (f16)a, (f16)b };
  return r;
#endif
}

// ---------------- cast f32 -> f16 (vectorized) ----------------
__global__ __launch_bounds__(256) void cast_kernel(const float4* __restrict__ src,
                                                   f16x4* __restrict__ dst, int n4){
  int i = blockIdx.x*blockDim.x + threadIdx.x;
  int stride = gridDim.x*blockDim.x;
  for (; i < n4; i += stride){
    float4 v = src[i];
    f16x4 o = { (f16)v.x, (f16)v.y, (f16)v.z, (f16)v.w };
    dst[i] = o;
  }
}

// ---------------- GEMM: Y[m][n] = sum_k X[m][k] * W[n][k] ----------------
#define BM 128
#define BN 128
#define BK 32

__global__ __launch_bounds__(256) void gemm_xwT(const f16* __restrict__ A,  // MROWS x DIMK
                                                const f16* __restrict__ B,  // NPROJ x DIMK
                                                f16* __restrict__ C){       // MROWS x NPROJ
  __shared__ f16 sA[BM*BK];
  __shared__ f16 sB[BN*BK];
  const int t = threadIdx.x;
  const int w = t >> 6;
  const int l = t & 63;
  const int bm = blockIdx.x;
  const int bn = blockIdx.y;
  const int wr = w >> 1, wc = w & 1;

  f32x4 acc[4][4] = {};

  const int srow = t >> 2;
  const int scol = (t & 3) * 8;
  const f16* gA0 = A + (size_t)(bm*BM + srow)*DIMK + scol;
  const f16* gB0 = B + (size_t)(bn*BN + srow)*DIMK + scol;
  char* sAb = (char*)sA;
  char* sBb = (char*)sB;
  const int ldsw = w*1024;

  for (int kk = 0; kk < DIMK/BK; ++kk){
    const f16* pa = gA0 + kk*BK;
    const f16* pb = gB0 + kk*BK;
    load_lds_16B(pa,           sAb + ldsw);
    load_lds_16B(pa + 64*DIMK, sAb + ldsw + 4096);
    load_lds_16B(pb,           sBb + ldsw);
    load_lds_16B(pb + 64*DIMK, sBb + ldsw + 4096);
    __syncthreads();

    f16x8 af[4], bf[4];
    #pragma unroll
    for (int mi=0; mi<4; ++mi){
      int arow = wr*64 + mi*16 + (l & 15);
      af[mi] = *(const f16x8*)(sAb + arow*64 + (l>>4)*16);
    }
    #pragma unroll
    for (int ni=0; ni<4; ++ni){
      int brow = wc*64 + ni*16 + (l & 15);
      bf[ni] = *(const f16x8*)(sBb + brow*64 + (l>>4)*16);
    }
    #pragma unroll
    for (int mi=0; mi<4; ++mi)
      #pragma unroll
      for (int ni=0; ni<4; ++ni)
        acc[mi][ni] = __builtin_amdgcn_mfma_f32_16x16x32_f16(af[mi], bf[ni], acc[mi][ni], 0, 0, 0);
    __syncthreads();
  }

  const int crow0 = bm*BM + wr*64 + (l>>4)*4;
  const int ccol0 = bn*BN + wc*64 + (l & 15);
  #pragma unroll
  for (int mi=0; mi<4; ++mi)
    #pragma unroll
    for (int ni=0; ni<4; ++ni)
      #pragma unroll
      for (int r=0; r<4; ++r)
        C[(size_t)(crow0 + mi*16 + r)*NPROJ + ccol0 + ni*16] = (f16)acc[mi][ni][r];
}

// ---------------- prep: in-place kn = k/(||k||+eps), bs = sigmoid(braw + bias) ----------
__global__ __launch_bounds__(256) void prep_kernel(f16* __restrict__ Y,
                                                   const float* __restrict__ b_beta){
  int g = blockIdx.x*4 + (threadIdx.x >> 6);   // [0, T*B*H)
  int l = threadIdx.x & 63;
  int h = g & 7;
  f16* y = Y + (size_t)(g >> 3)*NPROJ + h*NHEAD + l;
  float k  = (float)y[0];
  float br = (float)y[1536];
  float ss = k*k;
  #pragma unroll
  for (int d=1; d<64; d<<=1) ss += __shfl_xor(ss, d);
  y[0]    = (f16)(k * __builtin_amdgcn_rcpf(__builtin_sqrtf(ss) + 1e-6f));
  y[1536] = (f16)sigmoid_fast(br + b_beta[h*NHEAD + l]);
}

// ---------------- recurrent scan: 1024 threads/pair, packed f16 dots ----------------
// thread t: row = t>>4 (0..63), col group g = t&15 owns cols [g*4, g*4+4).
// Reductions: 4-stage shfl_xor within the row's 16 lanes. No LDS, no barriers.
struct Stage { f16x2 kl, kh, ql, qh; float v, bb; };

__device__ __forceinline__ Stage load_stage(const f16* base, int tn, int cb, int row){
  const f16* pn = base + (size_t)tn * (BATCH*NPROJ);
  Stage s;
  uint2 ku = *(const uint2*)(pn + cb);
  uint2 qu = *(const uint2*)(pn + 1024 + cb);
  s.kl = __builtin_bit_cast(f16x2, ku.x);
  s.kh = __builtin_bit_cast(f16x2, ku.y);
  s.ql = __builtin_bit_cast(f16x2, qu.x);
  s.qh = __builtin_bit_cast(f16x2, qu.y);
  s.v  = (float)pn[512 + row];
  s.bb = (float)pn[1536 + row];
  return s;
}

__device__ __forceinline__ void step_compute(const Stage& st, int tt, int g,
                                             float& S0, float& S1, float& S2, float& S3,
                                             f16x2& P0, f16x2& P1,
                                             float* outp){
  float kf0 = (float)st.kl[0], kf1 = (float)st.kl[1];
  float kf2 = (float)st.kh[0], kf3 = (float)st.kh[1];

  float r = fdot2(P0, st.kl, 0.f);
  r = fdot2(P1, st.kh, r);
  r += __shfl_xor(r, 1);
  r += __shfl_xor(r, 2);
  r += __shfl_xor(r, 4);
  r += __shfl_xor(r, 8);
  float delta = st.v - r;

  float a0 = tanh_fast(fmaf(st.bb, S0, delta*kf0));
  float a1 = tanh_fast(fmaf(st.bb, S1, delta*kf1));
  float a2 = tanh_fast(fmaf(st.bb, S2, delta*kf2));
  float a3 = tanh_fast(fmaf(st.bb, S3, delta*kf3));
  S0=a0; S1=a1; S2=a2; S3=a3;
  P0 = pack2(a0, a1);
  P1 = pack2(a2, a3);

  float sq = fdot2(P0, st.ql, 0.f);
  sq = fdot2(P1, st.qh, sq);
  sq += __shfl_xor(sq, 1);
  sq += __shfl_xor(sq, 2);
  sq += __shfl_xor(sq, 4);
  sq += __shfl_xor(sq, 8);
  if (g == 0){
    float sg = sigmoid_fast(sq);
    outp[(size_t)tt * (BATCH*512)] = sq*sq*sg;   // Sq * silu(Sq)
  }
}

__global__ __launch_bounds__(1024) void scan_kernel(const f16* __restrict__ Y,
                                                    float* __restrict__ out,
                                                    float* __restrict__ S_out){
  const int p = blockIdx.x;          // pair 0..255
  const int b = p >> 3, h = p & 7;
  const int t = threadIdx.x;         // 0..1023
  const int row = t >> 4;
  const int g   = t & 15;
  const int cb  = g*4;

  float S0=0.f, S1=0.f, S2=0.f, S3=0.f;
  f16x2 P0 = {}, P1 = {};

  const f16* base = Y + (size_t)b*NPROJ + h*NHEAD;
  float* outp = out + (size_t)b*512 + h*NHEAD + row;

  Stage sA = load_stage(base, 0, cb, row);
  Stage sB = load_stage(base, 1, cb, row);
  Stage sC, sD;

  #pragma unroll 1
  for (int tt=0; tt<TSTEPS; tt+=4){
    sC = load_stage(base, min(tt+2, TSTEPS-1), cb, row);
    step_compute(sA, tt,   g, S0,S1,S2,S3, P0,P1, outp);
    sD = load_stage(base, min(tt+3, TSTEPS-1), cb, row);
    step_compute(sB, tt+1, g, S0,S1,S2,S3, P0,P1, outp);
    sA = load_stage(base, min(tt+4, TSTEPS-1), cb, row);
    step_compute(sC, tt+2, g, S0,S1,S2,S3, P0,P1, outp);
    sB = load_stage(base, min(tt+5, TSTEPS-1), cb, row);
    step_compute(sD, tt+3, g, S0,S1,S2,S3, P0,P1, outp);
  }

  // S_final: [B, H, n, n]
  size_t sbase = ((size_t)p*NHEAD + row)*NHEAD + cb;
  float4 v4 = { S0, S1, S2, S3 };
  *(float4*)(S_out + sbase) = v4;
}

// ---------------- launch ----------------
extern "C" void kernel_launch(void* const* d_in, const int* in_sizes, int n_in,
                              void* d_out, int out_size, void* d_ws, size_t ws_size,
                              hipStream_t stream){
  const float* x  = (const float*)d_in[0];
  const float* Wk = (const float*)d_in[1];
  const float* Wv = (const float*)d_in[2];
  const float* Wq = (const float*)d_in[3];
  const float* Wb = (const float*)d_in[4];
  const float* bb = (const float*)d_in[5];

  float* out = (float*)d_out;
  float* Sf  = out + (size_t)TSTEPS*BATCH*512;

  char* ws = (char*)d_ws;
  f16* xh = (f16*)ws;                               // 64 MB
  f16* wh = (f16*)(ws + 67108864);                  // 4 MB
  f16* Yh = (f16*)(ws + 67108864 + 4194304);        // 128 MB

  cast_kernel<<<2048, 256, 0, stream>>>((const float4*)x,  (f16x4*)xh, (MROWS*DIMK)/4);
  cast_kernel<<<512,  256, 0, stream>>>((const float4*)Wk, (f16x4*)(wh + 0*524288), 524288/4);
  cast_kernel<<<512,  256, 0, stream>>>((const float4*)Wv, (f16x4*)(wh + 1*524288), 524288/4);
  cast_kernel<<<512,  256, 0, stream>>>((const float4*)Wq, (f16x4*)(wh + 2*524288), 524288/4);
  cast_kernel<<<512,  256, 0, stream>>>((const float4*)Wb, (f16x4*)(wh + 3*524288), 524288/4);

  dim3 g(MROWS/BM, NPROJ/BN);
  gemm_xwT<<<g, 256, 0, stream>>>(xh, wh, Yh);

  prep_kernel<<<(TSTEPS*BATCH*HEADS)/4, 256, 0, stream>>>(Yh, bb);

  scan_kernel<<<256, 1024, 0, stream>>>(Yh, out, Sf);
}

// Round 6
// 873.502 us; speedup vs baseline: 1.9339x; 1.1452x over previous
//
#include <hip/hip_runtime.h>
#include <stdint.h>

#define TSTEPS 1024
#define BATCH  32
#define DIMK   1024
#define HEADS  8
#define NHEAD  64
#define NPROJ  2048          // 4 * H * N
#define MROWS  (TSTEPS*BATCH)

typedef _Float16 f16;
typedef _Float16 f16x2 __attribute__((ext_vector_type(2)));
typedef _Float16 f16x4 __attribute__((ext_vector_type(4)));
typedef _Float16 f16x8 __attribute__((ext_vector_type(8)));
typedef float    f32x4 __attribute__((ext_vector_type(4)));
typedef unsigned int u32;

#define AS_GLOBAL __attribute__((address_space(1)))
#define AS_LDS    __attribute__((address_space(3)))

__device__ __forceinline__ void load_lds_16B(const void* g, void* l){
  __builtin_amdgcn_global_load_lds((const AS_GLOBAL u32*)g, (AS_LDS u32*)l, 16, 0, 0);
}

__device__ __forceinline__ float sigmoid_fast(float x){
  return __builtin_amdgcn_rcpf(1.0f + __expf(-x));
}
// tanh(x) = 1 - 2/(exp(2x)+1); saturates correctly at +-1
__device__ __forceinline__ float tanh_fast(float x){
  float e = __expf(2.0f*x);
  return fmaf(-2.0f, __builtin_amdgcn_rcpf(e + 1.0f), 1.0f);
}

__device__ __forceinline__ float fdot2(f16x2 a, f16x2 b, float c){
#if __has_builtin(__builtin_amdgcn_fdot2)
  typedef __fp16 h16x2 __attribute__((ext_vector_type(2)));
  return __builtin_amdgcn_fdot2(__builtin_bit_cast(h16x2, a),
                                __builtin_bit_cast(h16x2, b), c, false);
#else
  return fmaf((float)a[1], (float)b[1], fmaf((float)a[0], (float)b[0], c));
#endif
}

__device__ __forceinline__ f16x2 pack2(float a, float b){
#if __has_builtin(__builtin_amdgcn_cvt_pkrtz)
  return __builtin_bit_cast(f16x2, __builtin_amdgcn_cvt_pkrtz(a, b));
#else
  f16x2 r = { (f16)a, (f16)b };
  return r;
#endif
}

// ---------------- cast f32 -> f16 (vectorized) ----------------
__global__ __launch_bounds__(256) void cast_kernel(const float4* __restrict__ src,
                                                   f16x4* __restrict__ dst, int n4){
  int i = blockIdx.x*blockDim.x + threadIdx.x;
  int stride = gridDim.x*blockDim.x;
  for (; i < n4; i += stride){
    float4 v = src[i];
    f16x4 o = { (f16)v.x, (f16)v.y, (f16)v.z, (f16)v.w };
    dst[i] = o;
  }
}

// ---------------- GEMM: Y[m][n] = sum_k X[m][k] * W[n][k] ----------------
#define BM 128
#define BN 128
#define BK 32

__global__ __launch_bounds__(256) void gemm_xwT(const f16* __restrict__ A,  // MROWS x DIMK
                                                const f16* __restrict__ B,  // NPROJ x DIMK
                                                f16* __restrict__ C){       // MROWS x NPROJ
  __shared__ f16 sA[BM*BK];
  __shared__ f16 sB[BN*BK];
  const int t = threadIdx.x;
  const int w = t >> 6;
  const int l = t & 63;
  const int bm = blockIdx.x;
  const int bn = blockIdx.y;
  const int wr = w >> 1, wc = w & 1;

  f32x4 acc[4][4] = {};

  const int srow = t >> 2;
  const int scol = (t & 3) * 8;
  const f16* gA0 = A + (size_t)(bm*BM + srow)*DIMK + scol;
  const f16* gB0 = B + (size_t)(bn*BN + srow)*DIMK + scol;
  char* sAb = (char*)sA;
  char* sBb = (char*)sB;
  const int ldsw = w*1024;

  for (int kk = 0; kk < DIMK/BK; ++kk){
    const f16* pa = gA0 + kk*BK;
    const f16* pb = gB0 + kk*BK;
    load_lds_16B(pa,           sAb + ldsw);
    load_lds_16B(pa + 64*DIMK, sAb + ldsw + 4096);
    load_lds_16B(pb,           sBb + ldsw);
    load_lds_16B(pb + 64*DIMK, sBb + ldsw + 4096);
    __syncthreads();

    f16x8 af[4], bf[4];
    #pragma unroll
    for (int mi=0; mi<4; ++mi){
      int arow = wr*64 + mi*16 + (l & 15);
      af[mi] = *(const f16x8*)(sAb + arow*64 + (l>>4)*16);
    }
    #pragma unroll
    for (int ni=0; ni<4; ++ni){
      int brow = wc*64 + ni*16 + (l & 15);
      bf[ni] = *(const f16x8*)(sBb + brow*64 + (l>>4)*16);
    }
    #pragma unroll
    for (int mi=0; mi<4; ++mi)
      #pragma unroll
      for (int ni=0; ni<4; ++ni)
        acc[mi][ni] = __builtin_amdgcn_mfma_f32_16x16x32_f16(af[mi], bf[ni], acc[mi][ni], 0, 0, 0);
    __syncthreads();
  }

  const int crow0 = bm*BM + wr*64 + (l>>4)*4;
  const int ccol0 = bn*BN + wc*64 + (l & 15);
  #pragma unroll
  for (int mi=0; mi<4; ++mi)
    #pragma unroll
    for (int ni=0; ni<4; ++ni)
      #pragma unroll
      for (int r=0; r<4; ++r)
        C[(size_t)(crow0 + mi*16 + r)*NPROJ + ccol0 + ni*16] = (f16)acc[mi][ni][r];
}

// ---------------- prep: in-place kn = k/(||k||+eps), bs = sigmoid(braw + bias) ----------
__global__ __launch_bounds__(256) void prep_kernel(f16* __restrict__ Y,
                                                   const float* __restrict__ b_beta){
  int g = blockIdx.x*4 + (threadIdx.x >> 6);   // [0, T*B*H)
  int l = threadIdx.x & 63;
  int h = g & 7;
  f16* y = Y + (size_t)(g >> 3)*NPROJ + h*NHEAD + l;
  float k  = (float)y[0];
  float br = (float)y[1536];
  float ss = k*k;
  #pragma unroll
  for (int d=1; d<64; d<<=1) ss += __shfl_xor(ss, d);
  y[0]    = (f16)(k * __builtin_amdgcn_rcpf(__builtin_sqrtf(ss) + 1e-6f));
  y[1536] = (f16)sigmoid_fast(br + b_beta[h*NHEAD + l]);
}

// ---------------- recurrent scan: 1024 threads/pair, packed f16 dots ----------------
// thread t: row = t>>4 (0..63), col group g = t&15 owns cols [g*4, g*4+4).
// Reductions: 4-stage shfl_xor within the row's 16 lanes. No LDS, no barriers.
// Y has 2 steps of tail slack so prefetch never needs clamping.
struct Stage { f16x2 kl, kh, ql, qh; float v, bb; };

__device__ __forceinline__ Stage load_stage(const f16* base, int tn, int cb, int row){
  const f16* pn = base + (size_t)tn * (BATCH*NPROJ);
  Stage s;
  uint2 ku = *(const uint2*)(pn + cb);
  uint2 qu = *(const uint2*)(pn + 1024 + cb);
  s.kl = __builtin_bit_cast(f16x2, ku.x);
  s.kh = __builtin_bit_cast(f16x2, ku.y);
  s.ql = __builtin_bit_cast(f16x2, qu.x);
  s.qh = __builtin_bit_cast(f16x2, qu.y);
  s.v  = (float)pn[512 + row];
  s.bb = (float)pn[1536 + row];
  return s;
}

__device__ __forceinline__ void step_compute(const Stage& st, int tt, int g,
                                             float& S0, float& S1, float& S2, float& S3,
                                             f16x2& P0, f16x2& P1,
                                             float* outp){
  float kf0 = (float)st.kl[0], kf1 = (float)st.kl[1];
  float kf2 = (float)st.kh[0], kf3 = (float)st.kh[1];

  float r = fdot2(P0, st.kl, 0.f);
  r = fdot2(P1, st.kh, r);
  r += __shfl_xor(r, 1);
  r += __shfl_xor(r, 2);
  r += __shfl_xor(r, 4);
  r += __shfl_xor(r, 8);
  float delta = st.v - r;

  float a0 = tanh_fast(fmaf(st.bb, S0, delta*kf0));
  float a1 = tanh_fast(fmaf(st.bb, S1, delta*kf1));
  float a2 = tanh_fast(fmaf(st.bb, S2, delta*kf2));
  float a3 = tanh_fast(fmaf(st.bb, S3, delta*kf3));
  S0=a0; S1=a1; S2=a2; S3=a3;
  P0 = pack2(a0, a1);
  P1 = pack2(a2, a3);

  float sq = fdot2(P0, st.ql, 0.f);
  sq = fdot2(P1, st.qh, sq);
  sq += __shfl_xor(sq, 1);
  sq += __shfl_xor(sq, 2);
  sq += __shfl_xor(sq, 4);
  sq += __shfl_xor(sq, 8);
  // silu computed by all lanes (sq uniform in row group); store masked
  float sg = sigmoid_fast(sq);
  float o  = sq*sq*sg;
  if (g == 0) outp[(size_t)tt * (BATCH*512)] = o;
}

__global__ __launch_bounds__(1024) void scan_kernel(const f16* __restrict__ Y,
                                                    float* __restrict__ out,
                                                    float* __restrict__ S_out){
  const int p = blockIdx.x;          // pair 0..255
  const int b = p >> 3, h = p & 7;
  const int t = threadIdx.x;         // 0..1023
  const int row = t >> 4;
  const int g   = t & 15;
  const int cb  = g*4;

  float S0=0.f, S1=0.f, S2=0.f, S3=0.f;
  f16x2 P0 = {}, P1 = {};

  const f16* base = Y + (size_t)b*NPROJ + h*NHEAD;
  float* outp = out + (size_t)b*512 + h*NHEAD + row;

  Stage sA = load_stage(base, 0, cb, row);
  Stage sB = load_stage(base, 1, cb, row);
  Stage sC, sD;

  #pragma unroll 1
  for (int tt=0; tt<TSTEPS; tt+=4){
    sC = load_stage(base, tt+2, cb, row);
    step_compute(sA, tt,   g, S0,S1,S2,S3, P0,P1, outp);
    sD = load_stage(base, tt+3, cb, row);
    step_compute(sB, tt+1, g, S0,S1,S2,S3, P0,P1, outp);
    sA = load_stage(base, tt+4, cb, row);     // tail loads hit slack region, never consumed
    step_compute(sC, tt+2, g, S0,S1,S2,S3, P0,P1, outp);
    sB = load_stage(base, tt+5, cb, row);
    step_compute(sD, tt+3, g, S0,S1,S2,S3, P0,P1, outp);
  }

  // S_final: [B, H, n, n]
  size_t sbase = ((size_t)p*NHEAD + row)*NHEAD + cb;
  float4 v4 = { S0, S1, S2, S3 };
  *(float4*)(S_out + sbase) = v4;
}

// ---------------- launch ----------------
extern "C" void kernel_launch(void* const* d_in, const int* in_sizes, int n_in,
                              void* d_out, int out_size, void* d_ws, size_t ws_size,
                              hipStream_t stream){
  const float* x  = (const float*)d_in[0];
  const float* Wk = (const float*)d_in[1];
  const float* Wv = (const float*)d_in[2];
  const float* Wq = (const float*)d_in[3];
  const float* Wb = (const float*)d_in[4];
  const float* bb = (const float*)d_in[5];

  float* out = (float*)d_out;
  float* Sf  = out + (size_t)TSTEPS*BATCH*512;

  char* ws = (char*)d_ws;
  f16* xh = (f16*)ws;                               // 64 MB
  f16* wh = (f16*)(ws + 67108864);                  // 4 MB
  f16* Yh = (f16*)(ws + 67108864 + 4194304);        // 128 MB + 256 KB slack

  cast_kernel<<<2048, 256, 0, stream>>>((const float4*)x,  (f16x4*)xh, (MROWS*DIMK)/4);
  cast_kernel<<<512,  256, 0, stream>>>((const float4*)Wk, (f16x4*)(wh + 0*524288), 524288/4);
  cast_kernel<<<512,  256, 0, stream>>>((const float4*)Wv, (f16x4*)(wh + 1*524288), 524288/4);
  cast_kernel<<<512,  256, 0, stream>>>((const float4*)Wq, (f16x4*)(wh + 2*524288), 524288/4);
  cast_kernel<<<512,  256, 0, stream>>>((const float4*)Wb, (f16x4*)(wh + 3*524288), 524288/4);

  dim3 g(MROWS/BM, NPROJ/BN);
  gemm_xwT<<<g, 256, 0, stream>>>(xh, wh, Yh);

  prep_kernel<<<(TSTEPS*BATCH*HEADS)/4, 256, 0, stream>>>(Yh, bb);

  scan_kernel<<<256, 1024, 0, stream>>>(Yh, out, Sf);
}

// Round 7
// 800.231 us; speedup vs baseline: 2.1110x; 1.0916x over previous
//
#include <hip/hip_runtime.h>
#include <stdint.h>

#define TSTEPS 1024
#define BATCH  32
#define DIMK   1024
#define HEADS  8
#define NHEAD  64
#define NPROJ  2048          // 4 * H * N
#define MROWS  (TSTEPS*BATCH)

typedef _Float16 f16;
typedef _Float16 f16x2 __attribute__((ext_vector_type(2)));
typedef _Float16 f16x4 __attribute__((ext_vector_type(4)));
typedef _Float16 f16x8 __attribute__((ext_vector_type(8)));
typedef float    f32x2 __attribute__((ext_vector_type(2)));
typedef float    f32x4 __attribute__((ext_vector_type(4)));
typedef unsigned int u32;

#define AS_GLOBAL __attribute__((address_space(1)))
#define AS_LDS    __attribute__((address_space(3)))

#define C2LOG2E 2.8853900817779268f   // 2*log2(e)

__device__ __forceinline__ void load_lds_16B(const void* g, void* l){
  __builtin_amdgcn_global_load_lds((const AS_GLOBAL u32*)g, (AS_LDS u32*)l, 16, 0, 0);
}

__device__ __forceinline__ float sigmoid_fast(float x){
  return __builtin_amdgcn_rcpf(1.0f + __expf(-x));
}

__device__ __forceinline__ float exp2_fast(float x){
#if __has_builtin(__builtin_amdgcn_exp2f)
  return __builtin_amdgcn_exp2f(x);
#else
  return __expf(0.6931471805599453f * x);
#endif
}

__device__ __forceinline__ float fdot2(f16x2 a, f16x2 b, float c){
#if __has_builtin(__builtin_amdgcn_fdot2)
  typedef __fp16 h16x2 __attribute__((ext_vector_type(2)));
  return __builtin_amdgcn_fdot2(__builtin_bit_cast(h16x2, a),
                                __builtin_bit_cast(h16x2, b), c, false);
#else
  return fmaf((float)a[1], (float)b[1], fmaf((float)a[0], (float)b[0], c));
#endif
}

__device__ __forceinline__ f16x2 pack2(float a, float b){
#if __has_builtin(__builtin_amdgcn_cvt_pkrtz)
  return __builtin_bit_cast(f16x2, __builtin_amdgcn_cvt_pkrtz(a, b));
#else
  f16x2 r = { (f16)a, (f16)b };
  return r;
#endif
}

// ---------------- cast f32 -> f16 (vectorized) ----------------
__global__ __launch_bounds__(256) void cast_kernel(const float4* __restrict__ src,
                                                   f16x4* __restrict__ dst, int n4){
  int i = blockIdx.x*blockDim.x + threadIdx.x;
  int stride = gridDim.x*blockDim.x;
  for (; i < n4; i += stride){
    float4 v = src[i];
    f16x4 o = { (f16)v.x, (f16)v.y, (f16)v.z, (f16)v.w };
    dst[i] = o;
  }
}

// ---------------- GEMM: Y[m][n] = sum_k X[m][k] * W[n][k] ----------------
#define BM 128
#define BN 128
#define BK 32

__global__ __launch_bounds__(256) void gemm_xwT(const f16* __restrict__ A,  // MROWS x DIMK
                                                const f16* __restrict__ B,  // NPROJ x DIMK
                                                f16* __restrict__ C){       // MROWS x NPROJ
  __shared__ f16 sA[BM*BK];
  __shared__ f16 sB[BN*BK];
  const int t = threadIdx.x;
  const int w = t >> 6;
  const int l = t & 63;
  const int bm = blockIdx.x;
  const int bn = blockIdx.y;
  const int wr = w >> 1, wc = w & 1;

  f32x4 acc[4][4] = {};

  const int srow = t >> 2;
  const int scol = (t & 3) * 8;
  const f16* gA0 = A + (size_t)(bm*BM + srow)*DIMK + scol;
  const f16* gB0 = B + (size_t)(bn*BN + srow)*DIMK + scol;
  char* sAb = (char*)sA;
  char* sBb = (char*)sB;
  const int ldsw = w*1024;

  for (int kk = 0; kk < DIMK/BK; ++kk){
    const f16* pa = gA0 + kk*BK;
    const f16* pb = gB0 + kk*BK;
    load_lds_16B(pa,           sAb + ldsw);
    load_lds_16B(pa + 64*DIMK, sAb + ldsw + 4096);
    load_lds_16B(pb,           sBb + ldsw);
    load_lds_16B(pb + 64*DIMK, sBb + ldsw + 4096);
    __syncthreads();

    f16x8 af[4], bf[4];
    #pragma unroll
    for (int mi=0; mi<4; ++mi){
      int arow = wr*64 + mi*16 + (l & 15);
      af[mi] = *(const f16x8*)(sAb + arow*64 + (l>>4)*16);
    }
    #pragma unroll
    for (int ni=0; ni<4; ++ni){
      int brow = wc*64 + ni*16 + (l & 15);
      bf[ni] = *(const f16x8*)(sBb + brow*64 + (l>>4)*16);
    }
    #pragma unroll
    for (int mi=0; mi<4; ++mi)
      #pragma unroll
      for (int ni=0; ni<4; ++ni)
        acc[mi][ni] = __builtin_amdgcn_mfma_f32_16x16x32_f16(af[mi], bf[ni], acc[mi][ni], 0, 0, 0);
    __syncthreads();
  }

  const int crow0 = bm*BM + wr*64 + (l>>4)*4;
  const int ccol0 = bn*BN + wc*64 + (l & 15);
  #pragma unroll
  for (int mi=0; mi<4; ++mi)
    #pragma unroll
    for (int ni=0; ni<4; ++ni)
      #pragma unroll
      for (int r=0; r<4; ++r)
        C[(size_t)(crow0 + mi*16 + r)*NPROJ + ccol0 + ni*16] = (f16)acc[mi][ni][r];
}

// ---------------- prep: in-place kn = k/(||k||+eps), bs = C2LOG2E*sigmoid(braw+bias) ----
__global__ __launch_bounds__(256) void prep_kernel(f16* __restrict__ Y,
                                                   const float* __restrict__ b_beta){
  int g = blockIdx.x*4 + (threadIdx.x >> 6);   // [0, T*B*H)
  int l = threadIdx.x & 63;
  int h = g & 7;
  f16* y = Y + (size_t)(g >> 3)*NPROJ + h*NHEAD + l;
  float k  = (float)y[0];
  float br = (float)y[1536];
  float ss = k*k;
  #pragma unroll
  for (int d=1; d<64; d<<=1) ss += __shfl_xor(ss, d);
  y[0]    = (f16)(k * __builtin_amdgcn_rcpf(__builtin_sqrtf(ss) + 1e-6f));
  y[1536] = (f16)(C2LOG2E * sigmoid_fast(br + b_beta[h*NHEAD + l]));
}

// ---------------- recurrent scan: 1024 threads/pair, pk-f32 tanh path ----------------
// thread t: row = t>>4 (0..63), col group g = t&15 owns cols [g*4, g*4+4).
// tanh(x) computed as 1 - 2/(2^(C2LOG2E*x) + 1); beta pre-scaled, delta scaled 1x/step.
// Stores RAW sq; silu applied in a memory-bound postpass.
struct Stage { f16x2 kl, kh, ql, qh; float v, bb; };

__device__ __forceinline__ Stage load_stage(const f16* base, int tn, int cb, int row){
  const f16* pn = base + (size_t)tn * (BATCH*NPROJ);
  Stage s;
  uint2 ku = *(const uint2*)(pn + cb);
  uint2 qu = *(const uint2*)(pn + 1024 + cb);
  s.kl = __builtin_bit_cast(f16x2, ku.x);
  s.kh = __builtin_bit_cast(f16x2, ku.y);
  s.ql = __builtin_bit_cast(f16x2, qu.x);
  s.qh = __builtin_bit_cast(f16x2, qu.y);
  s.v  = (float)pn[512 + row];
  s.bb = (float)pn[1536 + row];   // pre-scaled by C2LOG2E
  return s;
}

__device__ __forceinline__ void step_compute(const Stage& st, int tt, int g,
                                             f32x2& S01, f32x2& S23,
                                             f16x2& P0, f16x2& P1,
                                             float* outp){
  float r = fdot2(P1, st.kh, fdot2(P0, st.kl, 0.f));
  r += __shfl_xor(r, 1);
  r += __shfl_xor(r, 2);
  r += __shfl_xor(r, 4);
  r += __shfl_xor(r, 8);
  float dl = (st.v - r) * C2LOG2E;

  f32x2 d2  = { dl, dl };
  f32x2 bb2 = { st.bb, st.bb };
  f32x2 k01 = { (float)st.kl[0], (float)st.kl[1] };
  f32x2 k23 = { (float)st.kh[0], (float)st.kh[1] };
  f32x2 arg01 = bb2*S01 + d2*k01;     // v_pk_fma_f32 path
  f32x2 arg23 = bb2*S23 + d2*k23;

  f32x2 e01 = { exp2_fast(arg01.x), exp2_fast(arg01.y) };
  f32x2 e23 = { exp2_fast(arg23.x), exp2_fast(arg23.y) };
  f32x2 one2 = { 1.f, 1.f };
  e01 += one2;  e23 += one2;          // v_pk_add_f32
  f32x2 t01 = { __builtin_amdgcn_rcpf(e01.x), __builtin_amdgcn_rcpf(e01.y) };
  f32x2 t23 = { __builtin_amdgcn_rcpf(e23.x), __builtin_amdgcn_rcpf(e23.y) };
  f32x2 m2 = { -2.f, -2.f };
  S01 = m2*t01 + one2;                // v_pk_fma_f32
  S23 = m2*t23 + one2;
  P0 = pack2(S01.x, S01.y);
  P1 = pack2(S23.x, S23.y);

  float sq = fdot2(P1, st.qh, fdot2(P0, st.ql, 0.f));
  sq += __shfl_xor(sq, 1);
  sq += __shfl_xor(sq, 2);
  sq += __shfl_xor(sq, 4);
  sq += __shfl_xor(sq, 8);
  if (g == 0) outp[(size_t)tt * (BATCH*512)] = sq;   // raw sq; silu in postpass
}

__global__ __launch_bounds__(1024) void scan_kernel(const f16* __restrict__ Y,
                                                    float* __restrict__ out,
                                                    float* __restrict__ S_out){
  const int p = blockIdx.x;          // pair 0..255
  const int b = p >> 3, h = p & 7;
  const int t = threadIdx.x;         // 0..1023
  const int row = t >> 4;
  const int g   = t & 15;
  const int cb  = g*4;

  f32x2 S01 = {0.f, 0.f}, S23 = {0.f, 0.f};
  f16x2 P0 = {}, P1 = {};

  const f16* base = Y + (size_t)b*NPROJ + h*NHEAD;
  float* outp = out + (size_t)b*512 + h*NHEAD + row;

  Stage sA = load_stage(base, 0, cb, row);
  Stage sB = load_stage(base, 1, cb, row);
  Stage sC, sD;

  #pragma unroll 1
  for (int tt=0; tt<TSTEPS; tt+=4){
    sC = load_stage(base, tt+2, cb, row);
    step_compute(sA, tt,   g, S01,S23, P0,P1, outp);
    sD = load_stage(base, tt+3, cb, row);
    step_compute(sB, tt+1, g, S01,S23, P0,P1, outp);
    sA = load_stage(base, tt+4, cb, row);     // tail loads hit slack region, never consumed
    step_compute(sC, tt+2, g, S01,S23, P0,P1, outp);
    sB = load_stage(base, tt+5, cb, row);
    step_compute(sD, tt+3, g, S01,S23, P0,P1, outp);
  }

  // S_final: [B, H, n, n]
  size_t sbase = ((size_t)p*NHEAD + row)*NHEAD + cb;
  float4 v4 = { S01.x, S01.y, S23.x, S23.y };
  *(float4*)(S_out + sbase) = v4;
}

// ---------------- postpass: out = sq * silu(sq), in place ----------------
__global__ __launch_bounds__(256) void silu_kernel(float4* __restrict__ o, int n4){
  int i = blockIdx.x*blockDim.x + threadIdx.x;
  int stride = gridDim.x*blockDim.x;
  for (; i < n4; i += stride){
    float4 v = o[i];
    v.x = v.x*v.x*sigmoid_fast(v.x);
    v.y = v.y*v.y*sigmoid_fast(v.y);
    v.z = v.z*v.z*sigmoid_fast(v.z);
    v.w = v.w*v.w*sigmoid_fast(v.w);
    o[i] = v;
  }
}

// ---------------- launch ----------------
extern "C" void kernel_launch(void* const* d_in, const int* in_sizes, int n_in,
                              void* d_out, int out_size, void* d_ws, size_t ws_size,
                              hipStream_t stream){
  const float* x  = (const float*)d_in[0];
  const float* Wk = (const float*)d_in[1];
  const float* Wv = (const float*)d_in[2];
  const float* Wq = (const float*)d_in[3];
  const float* Wb = (const float*)d_in[4];
  const float* bb = (const float*)d_in[5];

  float* out = (float*)d_out;
  float* Sf  = out + (size_t)TSTEPS*BATCH*512;

  char* ws = (char*)d_ws;
  f16* xh = (f16*)ws;                               // 64 MB
  f16* wh = (f16*)(ws + 67108864);                  // 4 MB
  f16* Yh = (f16*)(ws + 67108864 + 4194304);        // 128 MB + slack

  cast_kernel<<<2048, 256, 0, stream>>>((const float4*)x,  (f16x4*)xh, (MROWS*DIMK)/4);
  cast_kernel<<<512,  256, 0, stream>>>((const float4*)Wk, (f16x4*)(wh + 0*524288), 524288/4);
  cast_kernel<<<512,  256, 0, stream>>>((const float4*)Wv, (f16x4*)(wh + 1*524288), 524288/4);
  cast_kernel<<<512,  256, 0, stream>>>((const float4*)Wq, (f16x4*)(wh + 2*524288), 524288/4);
  cast_kernel<<<512,  256, 0, stream>>>((const float4*)Wb, (f16x4*)(wh + 3*524288), 524288/4);

  dim3 g(MROWS/BM, NPROJ/BN);
  gemm_xwT<<<g, 256, 0, stream>>>(xh, wh, Yh);

  prep_kernel<<<(TSTEPS*BATCH*HEADS)/4, 256, 0, stream>>>(Yh, bb);

  scan_kernel<<<256, 1024, 0, stream>>>(Yh, out, Sf);

  silu_kernel<<<2048, 256, 0, stream>>>((float4*)out, (TSTEPS*BATCH*512)/4);
}